// Round 7
// baseline (481.515 us; speedup 1.0000x reference)
//
#include <hip/hip_runtime.h>
#include <hip/hip_bf16.h>
#include <math.h>

// ---------------------------------------------------------------------------
// ContMixT: f_concat -> conv3x3(d2) BN ReLU -> conv3x3(d4) BN ReLU -> pool ->
// 1x1 -> fc -> per-(batch,channel) 3x3 depthwise -> two 1x1 gates -> blend.
// conv1/conv2 run as bf16 MFMA implicit GEMM (m97-style: 128x128 tile, BK=64,
// global_load_lds width=16, xor-swizzled LDS).
// R1: pad_concat tiled transpose. R2: c0-outer/tap-inner + XCD swizzle
//     (FETCH 432->40MB, conv1 ~128us). R3: explicit dbuf REVERTED.
// R4: alpha+final fused (neutral). R5: register-resident alpha_final, gap
//     fused into pad_concat, border stores instead of in1p memset.
// R6: in-block split-K REVERTED (barrier coupling); dw LDS-tiled KEPT.
// R7: best-of-both baseline. [458us; conv1 133, tail ~282]
// R8: (a) conv1 CROSS-BLOCK split-K x3 (MODE 2): 1440 blocks of the identical
//     4-wave loop (36 K-steps each), raw fp32 partials + reduce kernel doing
//     fold+BN+ReLU+pack. Fixes the 1.9 blocks/CU TLP starvation without
//     touching the proven loop (R3/R6 lesson). Guarded on ws_size (needs
//     +94MB); falls back to MODE 0 if workspace too small.
//     (b) repack_w coalesced (contiguous reads + LDS transpose + 16B writes;
//     old version: 1.77M scattered 4B reads).
// ---------------------------------------------------------------------------

typedef __bf16 bf16x8 __attribute__((ext_vector_type(8)));
typedef float f32x4 __attribute__((ext_vector_type(4)));
typedef __attribute__((address_space(1))) void as1_void;
typedef __attribute__((address_space(3))) void as3_void;

// ---------------- small prep kernels ----------------

// BN folding: A = g/sqrt(v+eps), Bc = (conv_bias - m)*A + b  (256 threads)
__global__ __launch_bounds__(256) void prep_consts_kernel(
    const float* __restrict__ ob1, const float* __restrict__ g1, const float* __restrict__ b1,
    const float* __restrict__ m1, const float* __restrict__ v1,
    const float* __restrict__ ob2, const float* __restrict__ g2, const float* __restrict__ b2,
    const float* __restrict__ m2, const float* __restrict__ v2,
    float* __restrict__ cst)
{
  int i = threadIdx.x;
  float a1 = g1[i] / sqrtf(v1[i] + 1e-5f);
  cst[i]       = a1;
  cst[256 + i] = (ob1[i] - m1[i]) * a1 + b1[i];
  float a2 = g2[i] / sqrtf(v2[i] + 1e-5f);
  cst[512 + i] = a2;
  cst[768 + i] = (ob2[i] - m2[i]) * a2 + b2[i];
}

// NCHW fp32 x3 -> padded NHWC bf16 [b][y+2][x+2][c], c = [f_tm2 | f_tm1 | f_t]
// One block per (b, y, 128-channel group). Phase 1: float4 loads -> fp32 LDS
// [c][x] (stride 85) + border zero-stores (R5c). Phase 2: 8 LDS reads -> 16B
// store, plus per-channel row sums -> gapv atomics for f_t/f_tm1 (R5b).
__global__ __launch_bounds__(256) void pad_concat_kernel(
    const float* __restrict__ f2, const float* __restrict__ f1, const float* __restrict__ f0,
    __hip_bfloat16* __restrict__ out, float* __restrict__ gapv)
{
  int bid = blockIdx.x;
  const int cg = bid % 6; bid /= 6;
  const int y = bid % 48;
  const int b = bid / 48;

  __shared__ float tile[128 * 85];

  const float* src = (cg < 2) ? f2 : ((cg < 4) ? f1 : f0);
  const int ccbase = (cg & 1) * 128;
  const uint4 z4 = {0u, 0u, 0u, 0u};

  // phase 1: 128 c x 20 x4 = 2560 float4 loads, 10 per thread
#pragma unroll
  for (int it = 0; it < 10; it++) {
    const int idx = it * 256 + threadIdx.x;
    const int cl = idx / 20, x4 = idx % 20;
    const float4 v = *(const float4*)(src +
        (((size_t)b * 256 + ccbase + cl) * 48 + y) * 80 + x4 * 4);
    float* t = tile + cl * 85 + x4 * 4;
    t[0] = v.x; t[1] = v.y; t[2] = v.z; t[3] = v.w;
  }

  // R5c: x-borders of this padded row (x = 0,1,82,83), 128 ch = 32 uint4
  if (threadIdx.x < 32) {
    const int xb_ = threadIdx.x >> 3, ch8 = threadIdx.x & 7;
    const int xx = (xb_ < 2) ? xb_ : (80 + xb_);
    *(uint4*)(out + ((size_t)(b * 52 + y + 2) * 84 + xx) * 768 + cg * 128 + ch8 * 8) = z4;
  }
  // R5c: y-border rows (0,1 by y==0 blocks; 50,51 by y==47 blocks)
  if (y == 0 || y == 47) {
    const int r0 = (y == 0) ? 0 : 50;
    for (int idx = threadIdx.x; idx < 1344; idx += 256) {   // 2 rows x 84 x x 8
      const int rr = idx / 672, rem = idx % 672;
      const int xx = rem >> 3, ch8 = rem & 7;
      *(uint4*)(out + ((size_t)(b * 52 + r0 + rr) * 84 + xx) * 768 + cg * 128 + ch8 * 8) = z4;
    }
  }
  __syncthreads();

  // phase 2: 80 x x 16 chunks = 1280 16B stores, 5 per thread
  __hip_bfloat16* obase = out + ((size_t)(b * 52 + y + 2) * 84 + 2) * 768 + cg * 128;
#pragma unroll
  for (int it = 0; it < 5; it++) {
    const int idx = it * 256 + threadIdx.x;
    const int chunk = idx & 15, x = idx >> 4;
    const float* t = tile + chunk * 8 * 85 + x;
    union { __hip_bfloat16 h[8]; uint4 u; } pk;
#pragma unroll
    for (int j = 0; j < 8; j++) pk.h[j] = __float2bfloat16(t[j * 85]);
    *(uint4*)(obase + (size_t)x * 768 + chunk * 8) = pk.u;
  }

  // R5b: gap row-sums for f_t (cg 4,5 -> i=b) and f_tm1 (cg 2,3 -> i=b+8)
  if (cg >= 2) {
    const int i_gap = (cg >= 4) ? b : (b + 8);
    const int cl = threadIdx.x >> 1, half = threadIdx.x & 1;
    const float* t = tile + cl * 85 + half * 40;
    float s = 0.f;
#pragma unroll
    for (int k = 0; k < 40; k++) s += t[k];
    s += __shfl_xor(s, 1);
    if (half == 0) atomicAdd(&gapv[i_gap * 256 + ccbase + cl], s);
  }
}

// R8b: OIHW fp32 -> [tap][oc][ic] bf16, coalesced. Block = (oc, 128-ic chunk):
// reads oc's 1152 floats contiguously, LDS transpose (stride-9 reads, 9
// coprime 32 -> conflict-free), 16B packed writes.
__global__ __launch_bounds__(256) void repack_w_kernel(
    const float* __restrict__ w, __hip_bfloat16* __restrict__ out, int OC, int IC)
{
  const int nicb = IC >> 7;
  const int icb = blockIdx.x % nicb;
  const int oc  = blockIdx.x / nicb;
  const int ic0 = icb * 128;
  __shared__ float wl[1152];
  const float* src = w + ((size_t)oc * IC + ic0) * 9;
  for (int k = threadIdx.x; k < 1152; k += 256) wl[k] = src[k];
  __syncthreads();
  if (threadIdx.x < 144) {
    const int tap = threadIdx.x / 16, ch = threadIdx.x % 16;
    union { __hip_bfloat16 h[8]; uint4 u; } pk;
#pragma unroll
    for (int j = 0; j < 8; j++) pk.h[j] = __float2bfloat16(wl[(ch * 8 + j) * 9 + tap]);
    *(uint4*)(out + ((size_t)tap * OC + oc) * IC + ic0 + ch * 8) = pk.u;
  }
}

// ---------------- MFMA implicit-GEMM conv ----------------
// Tile: M=128 pixels (8 rows x 16 x) x N=128 oc, BK=64, 4 waves, wave = 64x64.
// A LDS [m][64c], B LDS [oc][64c], 128B rows, 16B-chunk xor swizzle
// (chunk col = j ^ (row&7)); global_load_lds contiguous-dst (m104) honored by
// permuting the *source* chunk per lane.
// K-loop: c0 OUTER, tap INNER (R2) — tap re-reads hit L2.
// MODE 0: full K; BN+ReLU -> bf16 NHWC padded(+4) store
// MODE 1: full K; BN+ReLU -> pooled per-(b,oc) sums via atomics
// MODE 2: split-K x3 (R8): this block does channels [kc*CIN/3,(kc+1)*CIN/3);
//         raw fp32 acc -> partial buffer pbuf[kc][pixel][oc].
template <int CIN, int HP, int WP, int DIL, int MODE>
__global__ __launch_bounds__(256) void conv_mfma_kernel(
    const __hip_bfloat16* __restrict__ inp, const __hip_bfloat16* __restrict__ wt,
    const float* __restrict__ bnA, const float* __restrict__ bnB,
    __hip_bfloat16* __restrict__ outp, float* __restrict__ gpool)
{
  __shared__ unsigned short As[8192] __attribute__((aligned(16)));
  __shared__ unsigned short Bs[8192] __attribute__((aligned(16)));

  // XCD swizzle (bijective). MODE 2: grid 1440 = 8*180, kc fastest so each
  // XCD holds all 3 kc-chunks + both ocb halves of one batch image.
  int bid = blockIdx.x;
  int kc = 0;
  if (MODE == 2) {
    bid = (bid & 7) * 180 + (bid >> 3);
    kc = bid % 3; bid /= 3;
  } else {
    bid = (bid & 7) * 60 + (bid >> 3);
  }
  const int ocb = bid & 1; bid >>= 1;
  const int xb = bid % 5; bid /= 5;
  const int yb = bid % 6; bid /= 6;
  const int b = bid;
  const int y0 = yb * 8, x0 = xb * 16, oc0 = ocb * 128;

  const int t = threadIdx.x;
  const int w = t >> 6, l = t & 63;
  const int col16 = l & 15, quad = l >> 4;
  const int wm = w >> 1, wn = w & 1;
  const int rsub = l >> 3;          // row within an 8-row staging chunk
  const int jj = (l & 7) ^ rsub;    // swizzled source 16B-chunk

  f32x4 acc[4][4];
  const f32x4 zf = {0.f, 0.f, 0.f, 0.f};
#pragma unroll
  for (int i = 0; i < 4; i++)
#pragma unroll
    for (int j = 0; j < 4; j++) acc[i][j] = zf;

  const int cbeg = (MODE == 2) ? kc * (CIN / 3) : 0;
  const int cend = (MODE == 2) ? cbeg + CIN / 3 : CIN;
  for (int c0 = cbeg; c0 < cend; c0 += 64) {
    for (int tap = 0; tap < 9; tap++) {
      const int ty = tap / 3, tx = tap - ty * 3;
      const __hip_bfloat16* inBase =
          inp + ((size_t)(b * HP + y0 + DIL * ty) * WP + (x0 + DIL * tx)) * CIN + jj * 8 + c0;
      const __hip_bfloat16* wBase = wt + (size_t)(tap * 256 + oc0) * CIN + jj * 8 + c0;
      __syncthreads();
#pragma unroll
      for (int i = 0; i < 4; i++) {            // A: 128 pixels x 64 ch
        const int q = i * 4 + w;
        const int m = q * 8 + rsub;
        const int ry = m >> 4, rx = m & 15;
        const __hip_bfloat16* gp = inBase + (ry * WP + rx) * CIN;
        __builtin_amdgcn_global_load_lds((as1_void*)gp,
            (as3_void*)((char*)As + q * 1024), 16, 0, 0);
      }
#pragma unroll
      for (int i = 0; i < 4; i++) {            // B: 128 oc x 64 ch
        const int q = i * 4 + w;
        const int n = q * 8 + rsub;
        const __hip_bfloat16* gp = wBase + n * CIN;
        __builtin_amdgcn_global_load_lds((as1_void*)gp,
            (as3_void*)((char*)Bs + q * 1024), 16, 0, 0);
      }
      __syncthreads();
#pragma unroll
      for (int kiter = 0; kiter < 2; kiter++) {
        bf16x8 af[4], bg[4];
#pragma unroll
        for (int fi = 0; fi < 4; fi++) {       // A frag: m = lane&15
          const int m = wm * 64 + fi * 16 + col16;
          const int jc = (kiter * 4 + quad) ^ (m & 7);
          af[fi] = *(const bf16x8*)((const char*)As + m * 128 + jc * 16);
        }
#pragma unroll
        for (int fi = 0; fi < 4; fi++) {       // B frag: n = lane&15
          const int n = wn * 64 + fi * 16 + col16;
          const int jc = (kiter * 4 + quad) ^ (n & 7);
          bg[fi] = *(const bf16x8*)((const char*)Bs + n * 128 + jc * 16);
        }
#pragma unroll
        for (int fm_ = 0; fm_ < 4; fm_++)
#pragma unroll
          for (int fn_ = 0; fn_ < 4; fn_++)
            acc[fm_][fn_] = __builtin_amdgcn_mfma_f32_16x16x32_bf16(
                af[fm_], bg[fn_], acc[fm_][fn_], 0, 0, 0);
      }
    }
  }

  if (MODE == 0) {
    // C/D layout: col = lane&15 (= oc), row = quad*4 + r (= pixel)  [m89/m91]
#pragma unroll
    for (int fn_ = 0; fn_ < 4; fn_++) {
      const int oc = oc0 + wn * 64 + fn_ * 16 + col16;
      const float sa = bnA[oc], sb = bnB[oc];
#pragma unroll
      for (int fm_ = 0; fm_ < 4; fm_++) {
#pragma unroll
        for (int r = 0; r < 4; r++) {
          const int m = wm * 64 + fm_ * 16 + quad * 4 + r;
          const int y = y0 + (m >> 4), x = x0 + (m & 15);
          const float v = fmaxf(acc[fm_][fn_][r] * sa + sb, 0.f);
          outp[((size_t)(b * 56 + y + 4) * 88 + (x + 4)) * 256 + oc] = __float2bfloat16(v);
        }
      }
    }
  } else if (MODE == 1) {
#pragma unroll
    for (int fn_ = 0; fn_ < 4; fn_++) {
      const int oc = oc0 + wn * 64 + fn_ * 16 + col16;
      const float sa = bnA[oc], sb = bnB[oc];
      float cs = 0.f;
#pragma unroll
      for (int fm_ = 0; fm_ < 4; fm_++)
#pragma unroll
        for (int r = 0; r < 4; r++)
          cs += fmaxf(acc[fm_][fn_][r] * sa + sb, 0.f);
      cs += __shfl_xor(cs, 16);   // combine the 4 quads holding this column
      cs += __shfl_xor(cs, 32);
      if (quad == 0) atomicAdd(&gpool[b * 256 + oc], cs);
    }
  } else {
    // MODE 2: raw partial store, pbuf (= gpool arg) [kc][pixel 0..30719][oc]
    float* pb = gpool + (size_t)kc * 7864320;
#pragma unroll
    for (int fn_ = 0; fn_ < 4; fn_++) {
      const int oc = oc0 + wn * 64 + fn_ * 16 + col16;
#pragma unroll
      for (int fm_ = 0; fm_ < 4; fm_++) {
#pragma unroll
        for (int r = 0; r < 4; r++) {
          const int m = wm * 64 + fm_ * 16 + quad * 4 + r;
          const int y = y0 + (m >> 4), x = x0 + (m & 15);
          const int p = (b * 48 + y) * 80 + x;
          pb[(size_t)p * 256 + oc] = acc[fm_][fn_][r];
        }
      }
    }
  }
}

// R8a: fold 3 split-K partials + BN + ReLU + bf16 pack -> h1p.
// 7680 blocks x 256 thr x 4 floats = 7,864,320 (pixel,oc) pairs.
__global__ __launch_bounds__(256) void reduce_split_kernel(
    const float* __restrict__ pbuf, const float* __restrict__ bnA,
    const float* __restrict__ bnB, __hip_bfloat16* __restrict__ outp)
{
  const size_t i4 = ((size_t)blockIdx.x * 256 + threadIdx.x) * 4;
  const float4 a = *(const float4*)(pbuf + i4);
  const float4 bq = *(const float4*)(pbuf + 7864320 + i4);
  const float4 c = *(const float4*)(pbuf + 2 * 7864320 + i4);
  const int oc = (int)(i4 & 255);
  const int p  = (int)(i4 >> 8);
  const int b = p / 3840, rem = p % 3840, y = rem / 80, x = rem % 80;
  const float4 sa = *(const float4*)(bnA + oc);
  const float4 sb = *(const float4*)(bnB + oc);
  union { __hip_bfloat16 h[4]; uint2 u; } pk;
  pk.h[0] = __float2bfloat16(fmaxf((a.x + bq.x + c.x) * sa.x + sb.x, 0.f));
  pk.h[1] = __float2bfloat16(fmaxf((a.y + bq.y + c.y) * sa.y + sb.y, 0.f));
  pk.h[2] = __float2bfloat16(fmaxf((a.z + bq.z + c.z) * sa.z + sb.z, 0.f));
  pk.h[3] = __float2bfloat16(fmaxf((a.w + bq.w + c.w) * sa.w + sb.w, 0.f));
  *(uint2*)(outp + ((size_t)(b * 56 + y + 4) * 88 + (x + 4)) * 256 + oc) = pk.u;
}

// ---------------- FC chain (fp32) ----------------

// G[b][oc] = g_b[oc] + sum_c gpool[b][c]/3840 * g_w[oc][c]
__global__ __launch_bounds__(256) void fcG_kernel(
    const float* __restrict__ gpool, const float* __restrict__ gw,
    const float* __restrict__ gb, float* __restrict__ G)
{
  int b = blockIdx.x, oc = threadIdx.x;
  __shared__ float pool[256];
  pool[oc] = gpool[b * 256 + oc] * (1.f / 3840.f);
  __syncthreads();
  float s = gb[oc];
  const float* wr = gw + oc * 256;
  for (int c2 = 0; c2 < 256; c2++) s += pool[c2] * wr[c2];
  G[b * 256 + oc] = s;
}

// out1[j][i] = silu(fc_in[i] . fc1_w[j] + b[j]); fc_in = [G[i/2] | gap[i]]
// gapv holds raw sums (R5b) -> scale by 1/3840 here.
__global__ __launch_bounds__(256) void fc1_kernel(
    const float* __restrict__ G, const float* __restrict__ gapv,
    const float* __restrict__ w, const float* __restrict__ bias,
    float* __restrict__ out1)
{
  __shared__ float fin[16][513];
  for (int idx = threadIdx.x; idx < 16 * 512; idx += 256) {
    int i = idx >> 9, k = idx & 511;
    fin[i][k] = (k < 256) ? G[(i >> 1) * 256 + k]
                          : gapv[i * 256 + (k - 256)] * (1.f / 3840.f);
  }
  __syncthreads();
  int g = blockIdx.x * 256 + threadIdx.x;
  int j = g >> 4, i = g & 15;
  float s = bias[j];
  const float* wr = w + j * 512;
  for (int k = 0; k < 512; k++) s += fin[i][k] * wr[k];
  out1[j * 16 + i] = s / (1.f + expf(-s));
}

// wdw[i][j] = out1[i] . fc2_w[j] + b[j]   (j in 0..2303)
__global__ __launch_bounds__(256) void fc2_kernel(
    const float* __restrict__ out1, const float* __restrict__ w,
    const float* __restrict__ bias, float* __restrict__ wdw)
{
  __shared__ float fin[16][513];
  for (int idx = threadIdx.x; idx < 16 * 512; idx += 256) {
    int i = idx >> 9, k = idx & 511;
    fin[i][k] = out1[k * 16 + i];
  }
  __syncthreads();
  int g = blockIdx.x * 256 + threadIdx.x;
  int j = g >> 4, i = g & 15;
  float s = bias[j];
  const float* wr = w + j * 512;
  for (int k = 0; k < 512; k++) s += fin[i][k] * wr[k];
  wdw[i * 2304 + j] = s;
}

// per-(i,c) 3x3 depthwise, pad 1: fm = dwconv(Fs, wdw)
// R6b: plane staged in zero-padded LDS [50][82] via float4 loads; compute
// 4 px/thread from LDS; float4 stores.
__global__ __launch_bounds__(256) void dw_kernel(
    const float* __restrict__ f0, const float* __restrict__ f1,
    const float* __restrict__ wdw, float* __restrict__ fm)
{
  int i = blockIdx.x >> 8, c = blockIdx.x & 255;
  const float* src = (i < 8) ? (f0 + ((size_t)i * 256 + c) * 3840)
                             : (f1 + ((size_t)(i - 8) * 256 + c) * 3840);
  float* dst = fm + ((size_t)i * 256 + c) * 3840;
  __shared__ float w9s[9];
  __shared__ float tile[50][82];
  for (int k = threadIdx.x; k < 4100; k += 256) ((float*)tile)[k] = 0.f;
  if (threadIdx.x < 9) w9s[threadIdx.x] = wdw[i * 2304 + c * 9 + threadIdx.x];
  __syncthreads();
  for (int k = threadIdx.x; k < 960; k += 256) {
    const float4 v = *(const float4*)(src + k * 4);
    const int y = k / 20, xx = (k % 20) * 4;
    float* tp = &tile[y + 1][xx + 1];
    tp[0] = v.x; tp[1] = v.y; tp[2] = v.z; tp[3] = v.w;
  }
  __syncthreads();
  for (int k = threadIdx.x; k < 960; k += 256) {
    const int y = k / 20, xx = (k % 20) * 4;
    float r0 = 0.f, r1 = 0.f, r2 = 0.f, r3 = 0.f;
#pragma unroll
    for (int dy = 0; dy < 3; dy++) {
      const float* row = &tile[y + dy][xx];
      const float w0 = w9s[dy * 3], w1 = w9s[dy * 3 + 1], w2 = w9s[dy * 3 + 2];
      r0 += w0 * row[0] + w1 * row[1] + w2 * row[2];
      r1 += w0 * row[1] + w1 * row[2] + w2 * row[3];
      r2 += w0 * row[2] + w1 * row[3] + w2 * row[4];
      r3 += w0 * row[3] + w1 * row[4] + w2 * row[5];
    }
    float4 o; o.x = r0; o.y = r1; o.z = r2; o.w = r3;
    *(float4*)(dst + k * 4) = o;
  }
}

// R5a: fused alpha + final, register-resident. 640 threads = 80 x-positions
// x 8 slices of 32 channels. Each thread loads its 3x32 values ONCE into
// registers, reduces, then blends from registers — no second read of fm/f2.
__global__ __launch_bounds__(640) void alpha_final_kernel(
    const float* __restrict__ fm, const float* __restrict__ f2,
    const float* __restrict__ apw, const float* __restrict__ apb,
    const float* __restrict__ aw, const float* __restrict__ ab,
    float* __restrict__ out)
{
  int b = blockIdx.x / 48, y = blockIdx.x % 48;
  int x = threadIdx.x % 80, g = threadIdx.x / 80;  // g in 0..7: 32-ch slices
  const float* ftm  = fm + ((size_t)(b * 256) + g * 32) * 3840 + y * 80 + x;
  const float* ft1m = fm + ((size_t)((b + 8) * 256) + g * 32) * 3840 + y * 80 + x;
  const float* ptm2 = f2 + ((size_t)(b * 256) + g * 32) * 3840 + y * 80 + x;

  float v0[32], v1[32], v2[32];
  float S = 0.f, T0 = 0.f, T1 = 0.f, T2 = 0.f;
#pragma unroll
  for (int cc = 0; cc < 32; cc++) {
    v0[cc] = ftm[(size_t)cc * 3840];
    v1[cc] = ft1m[(size_t)cc * 3840];
    v2[cc] = ptm2[(size_t)cc * 3840];
    const int c = g * 32 + cc;
    S  += apw[c] * v1[cc] + apw[256 + c] * v2[cc];
    T0 += aw[c] * v0[cc];
    T1 += aw[256 + c] * v1[cc];
    T2 += aw[256 + c] * v2[cc];
  }
  __shared__ float red[4][8][80];
  __shared__ float apl[80], alb[80];
  red[0][g][x] = S; red[1][g][x] = T0; red[2][g][x] = T1; red[3][g][x] = T2;
  __syncthreads();
  if (g == 0) {
    float s = 0.f, t0 = 0.f, t1 = 0.f, t2 = 0.f;
#pragma unroll
    for (int k = 0; k < 8; k++) {
      s += red[0][k][x]; t0 += red[1][k][x]; t1 += red[2][k][x]; t2 += red[3][k][x];
    }
    float ap = 0.3f + 0.4f / (1.f + expf(-(s + apb[0])));
    float A  = t0 + ap * t1 + (1.f - ap) * t2 + ab[0];
    float al = 0.6f + 0.3f / (1.f + expf(-A));
    apl[x] = ap; alb[x] = al;
  }
  __syncthreads();
  const float ap = apl[x], al = alb[x];
  float* ob = out + ((size_t)(b * 256) + g * 32) * 3840 + y * 80 + x;
#pragma unroll
  for (int cc = 0; cc < 32; cc++)
    ob[(size_t)cc * 3840] = al * v0[cc] + (1.f - al) * (ap * v1[cc] + (1.f - ap) * v2[cc]);
}

// ---------------- launcher ----------------

extern "C" void kernel_launch(void* const* d_in, const int* in_sizes, int n_in,
                              void* d_out, int out_size, void* d_ws, size_t ws_size,
                              hipStream_t stream)
{
  const float* f_tm2 = (const float*)d_in[0];
  const float* f_tm1 = (const float*)d_in[1];
  const float* f_t   = (const float*)d_in[2];
  const float* ov_w1 = (const float*)d_in[3];
  const float* ov_b1 = (const float*)d_in[4];
  const float* bn1_g = (const float*)d_in[5];
  const float* bn1_b = (const float*)d_in[6];
  const float* bn1_m = (const float*)d_in[7];
  const float* bn1_v = (const float*)d_in[8];
  const float* ov_w2 = (const float*)d_in[9];
  const float* ov_b2 = (const float*)d_in[10];
  const float* bn2_g = (const float*)d_in[11];
  const float* bn2_b = (const float*)d_in[12];
  const float* bn2_m = (const float*)d_in[13];
  const float* bn2_v = (const float*)d_in[14];
  const float* g_w   = (const float*)d_in[15];
  const float* g_b   = (const float*)d_in[16];
  const float* fc1_w = (const float*)d_in[17];
  const float* fc1_b = (const float*)d_in[18];
  const float* fc2_w = (const float*)d_in[19];
  const float* fc2_b = (const float*)d_in[20];
  const float* ap_w  = (const float*)d_in[21];
  const float* ap_b  = (const float*)d_in[22];
  const float* a_w   = (const float*)d_in[23];
  const float* a_b   = (const float*)d_in[24];

  // workspace layout (fm aliases in1p/wt1/wt2/h1p-head: those are dead by dw)
  char* ws = (char*)d_ws;
  float* fm            = (float*)ws;                    // 62,914,560 B
  __hip_bfloat16* in1p = (__hip_bfloat16*)ws;           // 53,673,984 B (8x52x84x768)
  __hip_bfloat16* wt1  = (__hip_bfloat16*)(ws + 53673984);  //  3,538,944 B
  __hip_bfloat16* wt2  = (__hip_bfloat16*)(ws + 57212928);  //  1,179,648 B
  __hip_bfloat16* h1p  = (__hip_bfloat16*)(ws + 58392576);  // 20,185,088 B (8x56x88x256)
  float* gpool         = (float*)(ws + 78577664);       //  8 KB
  float* gapv          = (float*)(ws + 78585856);       // 16 KB (contiguous after gpool)
  float* Gv            = (float*)(ws + 78602240);       //  8 KB
  float* out1          = (float*)(ws + 78610432);       // 32 KB
  float* wdw           = (float*)(ws + 78643200);       // 144 KB
  float* cst           = (float*)(ws + 79036416);       //  4 KB  -> ends 79,040,512
  float* pbuf          = (float*)(ws + 79040512);       // R8: 3 x 31,457,280 B (if avail)

  const bool doSplit = (ws_size >= (size_t)79040512 + 3u * 31457280u);

  hipMemsetAsync(h1p, 0, 20185088, stream);    // zero borders for conv2
  hipMemsetAsync(gpool, 0, 24576, stream);     // gpool (8KB) + gapv (16KB) accumulators

  prep_consts_kernel<<<1, 256, 0, stream>>>(ov_b1, bn1_g, bn1_b, bn1_m, bn1_v,
                                            ov_b2, bn2_g, bn2_b, bn2_m, bn2_v, cst);
  pad_concat_kernel<<<2304, 256, 0, stream>>>(f_tm2, f_tm1, f_t, in1p, gapv);
  repack_w_kernel<<<1536, 256, 0, stream>>>(ov_w1, wt1, 256, 768);
  repack_w_kernel<<<512, 256, 0, stream>>>(ov_w2, wt2, 256, 256);

  // conv1: 768ch dil=2 -> h1p (bf16, padded +4);  conv2: 256ch dil=4 -> pooled sums
  if (doSplit) {
    conv_mfma_kernel<768, 52, 84, 2, 2><<<1440, 256, 0, stream>>>(in1p, wt1, cst, cst + 256, nullptr, pbuf);
    reduce_split_kernel<<<7680, 256, 0, stream>>>(pbuf, cst, cst + 256, h1p);
  } else {
    conv_mfma_kernel<768, 52, 84, 2, 0><<<480, 256, 0, stream>>>(in1p, wt1, cst, cst + 256, h1p, nullptr);
  }
  conv_mfma_kernel<256, 56, 88, 4, 1><<<480, 256, 0, stream>>>(h1p, wt2, cst + 512, cst + 768, nullptr, gpool);

  fcG_kernel<<<8, 256, 0, stream>>>(gpool, g_w, g_b, Gv);
  fc1_kernel<<<32, 256, 0, stream>>>(Gv, gapv, fc1_w, fc1_b, out1);
  fc2_kernel<<<144, 256, 0, stream>>>(out1, fc2_w, fc2_b, wdw);
  dw_kernel<<<4096, 256, 0, stream>>>(f_t, f_tm1, wdw, fm);
  alpha_final_kernel<<<384, 640, 0, stream>>>(fm, f_tm2, ap_w, ap_b, a_w, a_b, (float*)d_out);
}

// Round 8
// 444.627 us; speedup vs baseline: 1.0830x; 1.0830x over previous
//
#include <hip/hip_runtime.h>
#include <hip/hip_bf16.h>
#include <math.h>

// ---------------------------------------------------------------------------
// ContMixT: f_concat -> conv3x3(d2) BN ReLU -> conv3x3(d4) BN ReLU -> pool ->
// 1x1 -> fc -> per-(batch,channel) 3x3 depthwise -> two 1x1 gates -> blend.
// conv1/conv2 run as bf16 MFMA implicit GEMM (m97-style: 128x128 tile, BK=64,
// global_load_lds width=16, xor-swizzled LDS).
// R1: pad_concat tiled transpose. R2: c0-outer/tap-inner + XCD swizzle
//     (FETCH 432->40MB, conv1 ~128us). R3: explicit dbuf REVERTED.
// R4: alpha+final fused (neutral). R5: register-resident alpha_final, gap
//     fused into pad_concat, border stores instead of in1p memset.
// R6: in-block split-K REVERTED; dw LDS-tiled KEPT. R7: baseline 458us.
// R8: cross-block split-K x3 NET-REGRESSED (481us): conv 133->118 but +94MB
//     partials + reduce pass. Occupancy 20->24% only — TLP theory falsified;
//     conv1 ~133us/36% MfmaUtil is the m97-structure ceiling (3rd confirm).
// R9: conv1 reverted to MODE 0; coalesced repack KEPT; prep+repack+zeroing
//     merged into one aux_kernel (saves 4 launches; h1p border-only zero,
//     4.5MB stores vs 20MB memset — interior is fully overwritten by conv1).
// ---------------------------------------------------------------------------

typedef __bf16 bf16x8 __attribute__((ext_vector_type(8)));
typedef float f32x4 __attribute__((ext_vector_type(4)));
typedef __attribute__((address_space(1))) void as1_void;
typedef __attribute__((address_space(3))) void as3_void;

// ---------------- aux: repack + zero + BN-fold (one launch) ----------------
// grid: [0,1536) repack wt1 (oc,128-ic chunk); [1536,2048) repack wt2;
// [2048,3136) h1p border zero; [3136,3142) gpool/gapv zero; [3142] BN fold.
__global__ __launch_bounds__(256) void aux_kernel(
    const float* __restrict__ w1, const float* __restrict__ w2,
    const float* __restrict__ ob1, const float* __restrict__ g1, const float* __restrict__ b1,
    const float* __restrict__ m1, const float* __restrict__ v1,
    const float* __restrict__ ob2, const float* __restrict__ g2, const float* __restrict__ b2,
    const float* __restrict__ m2, const float* __restrict__ v2,
    __hip_bfloat16* __restrict__ wt1, __hip_bfloat16* __restrict__ wt2,
    __hip_bfloat16* __restrict__ h1p, float* __restrict__ gzero,
    float* __restrict__ cst)
{
  __shared__ float wl[1152];
  const int bid = blockIdx.x;
  const uint4 z4 = {0u, 0u, 0u, 0u};

  if (bid < 2048) {
    // coalesced weight repack: OIHW fp32 -> [tap][oc][ic] bf16 (R8b)
    const float* w = (bid < 1536) ? w1 : w2;
    __hip_bfloat16* out = (bid < 1536) ? wt1 : wt2;
    const int IC = (bid < 1536) ? 768 : 256;
    const int lb = (bid < 1536) ? bid : (bid - 1536);
    const int nicb = IC >> 7;
    const int icb = lb % nicb, oc = lb / nicb;
    const int ic0 = icb * 128;
    const float* src = w + ((size_t)oc * IC + ic0) * 9;
    for (int k = threadIdx.x; k < 1152; k += 256) wl[k] = src[k];
    __syncthreads();
    if (threadIdx.x < 144) {
      const int tap = threadIdx.x / 16, ch = threadIdx.x % 16;
      union { __hip_bfloat16 h[8]; uint4 u; } pk;
#pragma unroll
      for (int j = 0; j < 8; j++) pk.h[j] = __float2bfloat16(wl[(ch * 8 + j) * 9 + tap]);
      *(uint4*)(out + ((size_t)tap * 256 + oc) * IC + ic0 + ch * 8) = pk.u;
    }
  } else if (bid < 3136) {
    // h1p border zero: rows {0..3,52..55} all x, plus cols {0..3,84..87} for
    // rows 4..51. 8704 border px x 32 uint4 = 278528 stores = 1088 blocks.
    const int s = (bid - 2048) * 256 + threadIdx.x;
    const int px = s >> 5, ch8 = s & 31;
    const int b = px / 1088, r = px % 1088;
    int y, x;
    if (r < 704) { const int yi = r / 88; y = (yi < 4) ? yi : 48 + yi; x = r % 88; }
    else { const int r2 = r - 704; y = 4 + (r2 >> 3); const int xi = r2 & 7; x = (xi < 4) ? xi : 80 + xi; }
    *(uint4*)(h1p + ((size_t)(b * 56 + y) * 88 + x) * 256 + ch8 * 8) = z4;
  } else if (bid < 3142) {
    // gpool (8KB) + gapv (16KB) accumulators zero: 24576B = 1536 uint4
    ((uint4*)gzero)[(bid - 3136) * 256 + threadIdx.x] = z4;
  } else {
    // BN folding: A = g/sqrt(v+eps), Bc = (conv_bias - m)*A + b
    const int i = threadIdx.x;
    float a1 = g1[i] / sqrtf(v1[i] + 1e-5f);
    cst[i]       = a1;
    cst[256 + i] = (ob1[i] - m1[i]) * a1 + b1[i];
    float a2 = g2[i] / sqrtf(v2[i] + 1e-5f);
    cst[512 + i] = a2;
    cst[768 + i] = (ob2[i] - m2[i]) * a2 + b2[i];
  }
}

// NCHW fp32 x3 -> padded NHWC bf16 [b][y+2][x+2][c], c = [f_tm2 | f_tm1 | f_t]
// One block per (b, y, 128-channel group). Phase 1: float4 loads -> fp32 LDS
// [c][x] (stride 85) + border zero-stores (R5c). Phase 2: 8 LDS reads -> 16B
// store, plus per-channel row sums -> gapv atomics for f_t/f_tm1 (R5b).
__global__ __launch_bounds__(256) void pad_concat_kernel(
    const float* __restrict__ f2, const float* __restrict__ f1, const float* __restrict__ f0,
    __hip_bfloat16* __restrict__ out, float* __restrict__ gapv)
{
  int bid = blockIdx.x;
  const int cg = bid % 6; bid /= 6;
  const int y = bid % 48;
  const int b = bid / 48;

  __shared__ float tile[128 * 85];

  const float* src = (cg < 2) ? f2 : ((cg < 4) ? f1 : f0);
  const int ccbase = (cg & 1) * 128;
  const uint4 z4 = {0u, 0u, 0u, 0u};

  // phase 1: 128 c x 20 x4 = 2560 float4 loads, 10 per thread
#pragma unroll
  for (int it = 0; it < 10; it++) {
    const int idx = it * 256 + threadIdx.x;
    const int cl = idx / 20, x4 = idx % 20;
    const float4 v = *(const float4*)(src +
        (((size_t)b * 256 + ccbase + cl) * 48 + y) * 80 + x4 * 4);
    float* t = tile + cl * 85 + x4 * 4;
    t[0] = v.x; t[1] = v.y; t[2] = v.z; t[3] = v.w;
  }

  // R5c: x-borders of this padded row (x = 0,1,82,83), 128 ch = 32 uint4
  if (threadIdx.x < 32) {
    const int xb_ = threadIdx.x >> 3, ch8 = threadIdx.x & 7;
    const int xx = (xb_ < 2) ? xb_ : (80 + xb_);
    *(uint4*)(out + ((size_t)(b * 52 + y + 2) * 84 + xx) * 768 + cg * 128 + ch8 * 8) = z4;
  }
  // R5c: y-border rows (0,1 by y==0 blocks; 50,51 by y==47 blocks)
  if (y == 0 || y == 47) {
    const int r0 = (y == 0) ? 0 : 50;
    for (int idx = threadIdx.x; idx < 1344; idx += 256) {   // 2 rows x 84 x x 8
      const int rr = idx / 672, rem = idx % 672;
      const int xx = rem >> 3, ch8 = rem & 7;
      *(uint4*)(out + ((size_t)(b * 52 + r0 + rr) * 84 + xx) * 768 + cg * 128 + ch8 * 8) = z4;
    }
  }
  __syncthreads();

  // phase 2: 80 x x 16 chunks = 1280 16B stores, 5 per thread
  __hip_bfloat16* obase = out + ((size_t)(b * 52 + y + 2) * 84 + 2) * 768 + cg * 128;
#pragma unroll
  for (int it = 0; it < 5; it++) {
    const int idx = it * 256 + threadIdx.x;
    const int chunk = idx & 15, x = idx >> 4;
    const float* t = tile + chunk * 8 * 85 + x;
    union { __hip_bfloat16 h[8]; uint4 u; } pk;
#pragma unroll
    for (int j = 0; j < 8; j++) pk.h[j] = __float2bfloat16(t[j * 85]);
    *(uint4*)(obase + (size_t)x * 768 + chunk * 8) = pk.u;
  }

  // R5b: gap row-sums for f_t (cg 4,5 -> i=b) and f_tm1 (cg 2,3 -> i=b+8)
  if (cg >= 2) {
    const int i_gap = (cg >= 4) ? b : (b + 8);
    const int cl = threadIdx.x >> 1, half = threadIdx.x & 1;
    const float* t = tile + cl * 85 + half * 40;
    float s = 0.f;
#pragma unroll
    for (int k = 0; k < 40; k++) s += t[k];
    s += __shfl_xor(s, 1);
    if (half == 0) atomicAdd(&gapv[i_gap * 256 + ccbase + cl], s);
  }
}

// ---------------- MFMA implicit-GEMM conv ----------------
// Tile: M=128 pixels (8 rows x 16 x) x N=128 oc, BK=64, 4 waves, wave = 64x64.
// A LDS [m][64c], B LDS [oc][64c], 128B rows, 16B-chunk xor swizzle
// (chunk col = j ^ (row&7)); global_load_lds contiguous-dst (m104) honored by
// permuting the *source* chunk per lane.
// K-loop: c0 OUTER, tap INNER (R2) — tap re-reads hit L2.
// MODE 0: BN+ReLU -> bf16 NHWC padded(+4) store (conv1 -> conv2 input)
// MODE 1: BN+ReLU -> pooled per-(b,oc) sums via atomics (h2 never stored)
template <int CIN, int HP, int WP, int DIL, int MODE>
__global__ __launch_bounds__(256) void conv_mfma_kernel(
    const __hip_bfloat16* __restrict__ inp, const __hip_bfloat16* __restrict__ wt,
    const float* __restrict__ bnA, const float* __restrict__ bnB,
    __hip_bfloat16* __restrict__ outp, float* __restrict__ gpool)
{
  __shared__ unsigned short As[8192] __attribute__((aligned(16)));
  __shared__ unsigned short Bs[8192] __attribute__((aligned(16)));

  // XCD swizzle (grid=480=8*60, bijective): each XCD owns one batch image.
  int bid = blockIdx.x;
  bid = (bid & 7) * 60 + (bid >> 3);
  const int ocb = bid & 1; bid >>= 1;
  const int xb = bid % 5; bid /= 5;
  const int yb = bid % 6; bid /= 6;
  const int b = bid;
  const int y0 = yb * 8, x0 = xb * 16, oc0 = ocb * 128;

  const int t = threadIdx.x;
  const int w = t >> 6, l = t & 63;
  const int col16 = l & 15, quad = l >> 4;
  const int wm = w >> 1, wn = w & 1;
  const int rsub = l >> 3;          // row within an 8-row staging chunk
  const int jj = (l & 7) ^ rsub;    // swizzled source 16B-chunk

  f32x4 acc[4][4];
  const f32x4 zf = {0.f, 0.f, 0.f, 0.f};
#pragma unroll
  for (int i = 0; i < 4; i++)
#pragma unroll
    for (int j = 0; j < 4; j++) acc[i][j] = zf;

  for (int c0 = 0; c0 < CIN; c0 += 64) {
    for (int tap = 0; tap < 9; tap++) {
      const int ty = tap / 3, tx = tap - ty * 3;
      const __hip_bfloat16* inBase =
          inp + ((size_t)(b * HP + y0 + DIL * ty) * WP + (x0 + DIL * tx)) * CIN + jj * 8 + c0;
      const __hip_bfloat16* wBase = wt + (size_t)(tap * 256 + oc0) * CIN + jj * 8 + c0;
      __syncthreads();
#pragma unroll
      for (int i = 0; i < 4; i++) {            // A: 128 pixels x 64 ch
        const int q = i * 4 + w;
        const int m = q * 8 + rsub;
        const int ry = m >> 4, rx = m & 15;
        const __hip_bfloat16* gp = inBase + (ry * WP + rx) * CIN;
        __builtin_amdgcn_global_load_lds((as1_void*)gp,
            (as3_void*)((char*)As + q * 1024), 16, 0, 0);
      }
#pragma unroll
      for (int i = 0; i < 4; i++) {            // B: 128 oc x 64 ch
        const int q = i * 4 + w;
        const int n = q * 8 + rsub;
        const __hip_bfloat16* gp = wBase + n * CIN;
        __builtin_amdgcn_global_load_lds((as1_void*)gp,
            (as3_void*)((char*)Bs + q * 1024), 16, 0, 0);
      }
      __syncthreads();
#pragma unroll
      for (int kiter = 0; kiter < 2; kiter++) {
        bf16x8 af[4], bg[4];
#pragma unroll
        for (int fi = 0; fi < 4; fi++) {       // A frag: m = lane&15
          const int m = wm * 64 + fi * 16 + col16;
          const int jc = (kiter * 4 + quad) ^ (m & 7);
          af[fi] = *(const bf16x8*)((const char*)As + m * 128 + jc * 16);
        }
#pragma unroll
        for (int fi = 0; fi < 4; fi++) {       // B frag: n = lane&15
          const int n = wn * 64 + fi * 16 + col16;
          const int jc = (kiter * 4 + quad) ^ (n & 7);
          bg[fi] = *(const bf16x8*)((const char*)Bs + n * 128 + jc * 16);
        }
#pragma unroll
        for (int fm_ = 0; fm_ < 4; fm_++)
#pragma unroll
          for (int fn_ = 0; fn_ < 4; fn_++)
            acc[fm_][fn_] = __builtin_amdgcn_mfma_f32_16x16x32_bf16(
                af[fm_], bg[fn_], acc[fm_][fn_], 0, 0, 0);
      }
    }
  }

  if (MODE == 0) {
    // C/D layout: col = lane&15 (= oc), row = quad*4 + r (= pixel)  [m89/m91]
#pragma unroll
    for (int fn_ = 0; fn_ < 4; fn_++) {
      const int oc = oc0 + wn * 64 + fn_ * 16 + col16;
      const float sa = bnA[oc], sb = bnB[oc];
#pragma unroll
      for (int fm_ = 0; fm_ < 4; fm_++) {
#pragma unroll
        for (int r = 0; r < 4; r++) {
          const int m = wm * 64 + fm_ * 16 + quad * 4 + r;
          const int y = y0 + (m >> 4), x = x0 + (m & 15);
          const float v = fmaxf(acc[fm_][fn_][r] * sa + sb, 0.f);
          outp[((size_t)(b * 56 + y + 4) * 88 + (x + 4)) * 256 + oc] = __float2bfloat16(v);
        }
      }
    }
  } else {
#pragma unroll
    for (int fn_ = 0; fn_ < 4; fn_++) {
      const int oc = oc0 + wn * 64 + fn_ * 16 + col16;
      const float sa = bnA[oc], sb = bnB[oc];
      float cs = 0.f;
#pragma unroll
      for (int fm_ = 0; fm_ < 4; fm_++)
#pragma unroll
        for (int r = 0; r < 4; r++)
          cs += fmaxf(acc[fm_][fn_][r] * sa + sb, 0.f);
      cs += __shfl_xor(cs, 16);   // combine the 4 quads holding this column
      cs += __shfl_xor(cs, 32);
      if (quad == 0) atomicAdd(&gpool[b * 256 + oc], cs);
    }
  }
}

// ---------------- FC chain (fp32) ----------------

// G[b][oc] = g_b[oc] + sum_c gpool[b][c]/3840 * g_w[oc][c]
__global__ __launch_bounds__(256) void fcG_kernel(
    const float* __restrict__ gpool, const float* __restrict__ gw,
    const float* __restrict__ gb, float* __restrict__ G)
{
  int b = blockIdx.x, oc = threadIdx.x;
  __shared__ float pool[256];
  pool[oc] = gpool[b * 256 + oc] * (1.f / 3840.f);
  __syncthreads();
  float s = gb[oc];
  const float* wr = gw + oc * 256;
  for (int c2 = 0; c2 < 256; c2++) s += pool[c2] * wr[c2];
  G[b * 256 + oc] = s;
}

// out1[j][i] = silu(fc_in[i] . fc1_w[j] + b[j]); fc_in = [G[i/2] | gap[i]]
// gapv holds raw sums (R5b) -> scale by 1/3840 here.
__global__ __launch_bounds__(256) void fc1_kernel(
    const float* __restrict__ G, const float* __restrict__ gapv,
    const float* __restrict__ w, const float* __restrict__ bias,
    float* __restrict__ out1)
{
  __shared__ float fin[16][513];
  for (int idx = threadIdx.x; idx < 16 * 512; idx += 256) {
    int i = idx >> 9, k = idx & 511;
    fin[i][k] = (k < 256) ? G[(i >> 1) * 256 + k]
                          : gapv[i * 256 + (k - 256)] * (1.f / 3840.f);
  }
  __syncthreads();
  int g = blockIdx.x * 256 + threadIdx.x;
  int j = g >> 4, i = g & 15;
  float s = bias[j];
  const float* wr = w + j * 512;
  for (int k = 0; k < 512; k++) s += fin[i][k] * wr[k];
  out1[j * 16 + i] = s / (1.f + expf(-s));
}

// wdw[i][j] = out1[i] . fc2_w[j] + b[j]   (j in 0..2303)
__global__ __launch_bounds__(256) void fc2_kernel(
    const float* __restrict__ out1, const float* __restrict__ w,
    const float* __restrict__ bias, float* __restrict__ wdw)
{
  __shared__ float fin[16][513];
  for (int idx = threadIdx.x; idx < 16 * 512; idx += 256) {
    int i = idx >> 9, k = idx & 511;
    fin[i][k] = out1[k * 16 + i];
  }
  __syncthreads();
  int g = blockIdx.x * 256 + threadIdx.x;
  int j = g >> 4, i = g & 15;
  float s = bias[j];
  const float* wr = w + j * 512;
  for (int k = 0; k < 512; k++) s += fin[i][k] * wr[k];
  wdw[i * 2304 + j] = s;
}

// per-(i,c) 3x3 depthwise, pad 1: fm = dwconv(Fs, wdw)
// R6b: plane staged in zero-padded LDS [50][82] via float4 loads; compute
// 4 px/thread from LDS; float4 stores.
__global__ __launch_bounds__(256) void dw_kernel(
    const float* __restrict__ f0, const float* __restrict__ f1,
    const float* __restrict__ wdw, float* __restrict__ fm)
{
  int i = blockIdx.x >> 8, c = blockIdx.x & 255;
  const float* src = (i < 8) ? (f0 + ((size_t)i * 256 + c) * 3840)
                             : (f1 + ((size_t)(i - 8) * 256 + c) * 3840);
  float* dst = fm + ((size_t)i * 256 + c) * 3840;
  __shared__ float w9s[9];
  __shared__ float tile[50][82];
  for (int k = threadIdx.x; k < 4100; k += 256) ((float*)tile)[k] = 0.f;
  if (threadIdx.x < 9) w9s[threadIdx.x] = wdw[i * 2304 + c * 9 + threadIdx.x];
  __syncthreads();
  for (int k = threadIdx.x; k < 960; k += 256) {
    const float4 v = *(const float4*)(src + k * 4);
    const int y = k / 20, xx = (k % 20) * 4;
    float* tp = &tile[y + 1][xx + 1];
    tp[0] = v.x; tp[1] = v.y; tp[2] = v.z; tp[3] = v.w;
  }
  __syncthreads();
  for (int k = threadIdx.x; k < 960; k += 256) {
    const int y = k / 20, xx = (k % 20) * 4;
    float r0 = 0.f, r1 = 0.f, r2 = 0.f, r3 = 0.f;
#pragma unroll
    for (int dy = 0; dy < 3; dy++) {
      const float* row = &tile[y + dy][xx];
      const float w0 = w9s[dy * 3], w1 = w9s[dy * 3 + 1], w2 = w9s[dy * 3 + 2];
      r0 += w0 * row[0] + w1 * row[1] + w2 * row[2];
      r1 += w0 * row[1] + w1 * row[2] + w2 * row[3];
      r2 += w0 * row[2] + w1 * row[3] + w2 * row[4];
      r3 += w0 * row[3] + w1 * row[4] + w2 * row[5];
    }
    float4 o; o.x = r0; o.y = r1; o.z = r2; o.w = r3;
    *(float4*)(dst + k * 4) = o;
  }
}

// R5a: fused alpha + final, register-resident. 640 threads = 80 x-positions
// x 8 slices of 32 channels. Each thread loads its 3x32 values ONCE into
// registers, reduces, then blends from registers — no second read of fm/f2.
__global__ __launch_bounds__(640) void alpha_final_kernel(
    const float* __restrict__ fm, const float* __restrict__ f2,
    const float* __restrict__ apw, const float* __restrict__ apb,
    const float* __restrict__ aw, const float* __restrict__ ab,
    float* __restrict__ out)
{
  int b = blockIdx.x / 48, y = blockIdx.x % 48;
  int x = threadIdx.x % 80, g = threadIdx.x / 80;  // g in 0..7: 32-ch slices
  const float* ftm  = fm + ((size_t)(b * 256) + g * 32) * 3840 + y * 80 + x;
  const float* ft1m = fm + ((size_t)((b + 8) * 256) + g * 32) * 3840 + y * 80 + x;
  const float* ptm2 = f2 + ((size_t)(b * 256) + g * 32) * 3840 + y * 80 + x;

  float v0[32], v1[32], v2[32];
  float S = 0.f, T0 = 0.f, T1 = 0.f, T2 = 0.f;
#pragma unroll
  for (int cc = 0; cc < 32; cc++) {
    v0[cc] = ftm[(size_t)cc * 3840];
    v1[cc] = ft1m[(size_t)cc * 3840];
    v2[cc] = ptm2[(size_t)cc * 3840];
    const int c = g * 32 + cc;
    S  += apw[c] * v1[cc] + apw[256 + c] * v2[cc];
    T0 += aw[c] * v0[cc];
    T1 += aw[256 + c] * v1[cc];
    T2 += aw[256 + c] * v2[cc];
  }
  __shared__ float red[4][8][80];
  __shared__ float apl[80], alb[80];
  red[0][g][x] = S; red[1][g][x] = T0; red[2][g][x] = T1; red[3][g][x] = T2;
  __syncthreads();
  if (g == 0) {
    float s = 0.f, t0 = 0.f, t1 = 0.f, t2 = 0.f;
#pragma unroll
    for (int k = 0; k < 8; k++) {
      s += red[0][k][x]; t0 += red[1][k][x]; t1 += red[2][k][x]; t2 += red[3][k][x];
    }
    float ap = 0.3f + 0.4f / (1.f + expf(-(s + apb[0])));
    float A  = t0 + ap * t1 + (1.f - ap) * t2 + ab[0];
    float al = 0.6f + 0.3f / (1.f + expf(-A));
    apl[x] = ap; alb[x] = al;
  }
  __syncthreads();
  const float ap = apl[x], al = alb[x];
  float* ob = out + ((size_t)(b * 256) + g * 32) * 3840 + y * 80 + x;
#pragma unroll
  for (int cc = 0; cc < 32; cc++)
    ob[(size_t)cc * 3840] = al * v0[cc] + (1.f - al) * (ap * v1[cc] + (1.f - ap) * v2[cc]);
}

// ---------------- launcher ----------------

extern "C" void kernel_launch(void* const* d_in, const int* in_sizes, int n_in,
                              void* d_out, int out_size, void* d_ws, size_t ws_size,
                              hipStream_t stream)
{
  const float* f_tm2 = (const float*)d_in[0];
  const float* f_tm1 = (const float*)d_in[1];
  const float* f_t   = (const float*)d_in[2];
  const float* ov_w1 = (const float*)d_in[3];
  const float* ov_b1 = (const float*)d_in[4];
  const float* bn1_g = (const float*)d_in[5];
  const float* bn1_b = (const float*)d_in[6];
  const float* bn1_m = (const float*)d_in[7];
  const float* bn1_v = (const float*)d_in[8];
  const float* ov_w2 = (const float*)d_in[9];
  const float* ov_b2 = (const float*)d_in[10];
  const float* bn2_g = (const float*)d_in[11];
  const float* bn2_b = (const float*)d_in[12];
  const float* bn2_m = (const float*)d_in[13];
  const float* bn2_v = (const float*)d_in[14];
  const float* g_w   = (const float*)d_in[15];
  const float* g_b   = (const float*)d_in[16];
  const float* fc1_w = (const float*)d_in[17];
  const float* fc1_b = (const float*)d_in[18];
  const float* fc2_w = (const float*)d_in[19];
  const float* fc2_b = (const float*)d_in[20];
  const float* ap_w  = (const float*)d_in[21];
  const float* ap_b  = (const float*)d_in[22];
  const float* a_w   = (const float*)d_in[23];
  const float* a_b   = (const float*)d_in[24];

  // workspace layout (fm aliases in1p/wt1/wt2/h1p-head: those are dead by dw)
  char* ws = (char*)d_ws;
  float* fm            = (float*)ws;                    // 62,914,560 B
  __hip_bfloat16* in1p = (__hip_bfloat16*)ws;           // 53,673,984 B (8x52x84x768)
  __hip_bfloat16* wt1  = (__hip_bfloat16*)(ws + 53673984);  //  3,538,944 B
  __hip_bfloat16* wt2  = (__hip_bfloat16*)(ws + 57212928);  //  1,179,648 B
  __hip_bfloat16* h1p  = (__hip_bfloat16*)(ws + 58392576);  // 20,185,088 B (8x56x88x256)
  float* gpool         = (float*)(ws + 78577664);       //  8 KB
  float* gapv          = (float*)(ws + 78585856);       // 16 KB (contiguous after gpool)
  float* Gv            = (float*)(ws + 78602240);       //  8 KB
  float* out1          = (float*)(ws + 78610432);       // 32 KB
  float* wdw           = (float*)(ws + 78643200);       // 144 KB
  float* cst           = (float*)(ws + 79036416);       //  4 KB  (total ~75.4 MiB)

  // aux: repack wt1/wt2, zero h1p borders + gpool/gapv, fold BN consts
  aux_kernel<<<3143, 256, 0, stream>>>(ov_w1, ov_w2,
      ov_b1, bn1_g, bn1_b, bn1_m, bn1_v, ov_b2, bn2_g, bn2_b, bn2_m, bn2_v,
      wt1, wt2, h1p, gpool, cst);
  pad_concat_kernel<<<2304, 256, 0, stream>>>(f_tm2, f_tm1, f_t, in1p, gapv);

  // conv1: 768ch dil=2 -> h1p (bf16, padded +4);  conv2: 256ch dil=4 -> pooled sums
  conv_mfma_kernel<768, 52, 84, 2, 0><<<480, 256, 0, stream>>>(in1p, wt1, cst, cst + 256, h1p, nullptr);
  conv_mfma_kernel<256, 56, 88, 4, 1><<<480, 256, 0, stream>>>(h1p, wt2, cst + 512, cst + 768, nullptr, gpool);

  fcG_kernel<<<8, 256, 0, stream>>>(gpool, g_w, g_b, Gv);
  fc1_kernel<<<32, 256, 0, stream>>>(Gv, gapv, fc1_w, fc1_b, out1);
  fc2_kernel<<<144, 256, 0, stream>>>(out1, fc2_w, fc2_b, wdw);
  dw_kernel<<<4096, 256, 0, stream>>>(f_t, f_tm1, wdw, fm);
  alpha_final_kernel<<<384, 640, 0, stream>>>(fm, f_tm2, ap_w, ap_b, a_w, a_b, (float*)d_out);
}